// Round 2
// baseline (238.883 us; speedup 1.0000x reference)
//
#include <hip/hip_runtime.h>

#define SIGMA_INV 1.0e4f          // 1/SIGMA
#define GAMMA_INV 1.0e4f          // 1/GAMMA
#define ZNEAR 1.0f
#define ZFAR 100.0f
#define EPSV 1e-10f

constexpr int KF = 8;
constexpr int NPIX = 4 * 512 * 512;
constexpr int NPIX2 = NPIX / 2;
constexpr int NFACES = 200000;
// Dropped-slot relative weight <= e^LOG_CUT; worst-case amplification
// (prob ratio ~150 x normalize ~32x) -> ~5e-4, under the 3.9e-3 baseline.
#define LOG_CUT (-16.0f)
#define ZWIN (16.0f / GAMMA_INV)

// ---------------------------------------------------------------------------
// Kernel 1: pack the 3 vertex normals of each face into ONE uint4 (16 B).
// 9 components x 14-bit fixed point. Table = 3.2 MB -> L2-resident.
// ---------------------------------------------------------------------------
__global__ __launch_bounds__(256) void pack_face_normals14(
    const int*   __restrict__ faces,   // (F,3)
    const float* __restrict__ vnorm,   // (V,3)
    uint4*       __restrict__ fn,      // (F) packed
    int F)
{
    const int f = blockIdx.x * blockDim.x + threadIdx.x;
    if (f >= F) return;
    const int v[3] = { faces[f * 3 + 0], faces[f * 3 + 1], faces[f * 3 + 2] };

    unsigned long long lo = 0ull, hi = 0ull;
    int i = 0;
#pragma unroll
    for (int t = 0; t < 3; ++t) {
#pragma unroll
        for (int c = 0; c < 3; ++c, ++i) {
            const float x = vnorm[(size_t)v[t] * 3 + c];
            const unsigned long long code = (unsigned long long)(unsigned)
                __float2int_rn(fminf(fmaxf(x, -1.0f), 1.0f) * 8191.5f + 8191.5f);
            const int bp = 14 * i;
            if (bp < 64) {
                lo |= code << bp;
                if (bp > 50) hi |= code >> (64 - bp);
            } else {
                hi |= code << (bp - 64);
            }
        }
    }
    uint4 q;
    q.x = (unsigned)(lo & 0xFFFFFFFFull);
    q.y = (unsigned)(lo >> 32);
    q.z = (unsigned)(hi & 0xFFFFFFFFull);
    q.w = (unsigned)(hi >> 32);
    fn[f] = q;
}

__device__ __forceinline__ float dec14(const unsigned* w, int i) {
    const int bp = 14 * i;
    const int j = bp >> 5;
    const int off = bp & 31;
    unsigned long long u = (unsigned long long)w[j];
    if (j < 3) u |= (unsigned long long)w[j + 1] << 32;
    const unsigned code = (unsigned)(u >> off) & 0x3FFFu;
    return fmaf((float)code, 2.0f / 16383.0f, -1.0f);
}

__device__ __forceinline__ void acc_one(
    const uint4& q, float b0, float b1, float b2,
    float dv, float zsel, float zmax, float valid,
    float& ax, float& ay, float& az, float& wt)
{
    unsigned w[4] = { q.x, q.y, q.z, q.w };
    const float nx = b0 * dec14(w, 0) + b1 * dec14(w, 3) + b2 * dec14(w, 6);
    const float ny = b0 * dec14(w, 1) + b1 * dec14(w, 4) + b2 * dec14(w, 7);
    const float nz = b0 * dec14(w, 2) + b1 * dec14(w, 5) + b2 * dec14(w, 8);
    const float prob = 1.0f / (1.0f + __expf(dv * SIGMA_INV));
    const float wgt  = valid * prob * __expf((zsel - zmax) * GAMMA_INV);
    wt += wgt;
    ax = fmaf(wgt, nx, ax);
    ay = fmaf(wgt, ny, ay);
    az = fmaf(wgt, nz, az);
}

__device__ __forceinline__ void finish_pixel(
    float ax, float ay, float az, float wt, float zmax, float* o)
{
    const float delta = fmaxf(__expf((EPSV - zmax) * GAMMA_INV), EPSV);
    const float inv_denom = 1.0f / (wt + delta);
    const float r = (ax + delta) * inv_denom;   // bg = (1,1,1)
    const float g = (ay + delta) * inv_denom;
    const float b = (az + delta) * inv_denom;
    const float nrm = sqrtf(r * r + g * g + b * b);
    const float invn = 1.0f / fmaxf(nrm, 1e-12f);
    o[0] = fmaf(r * invn, 0.5f, 0.5f);
    o[1] = fmaf(g * invn, 0.5f, 0.5f);
    o[2] = fmaf(b * invn, 0.5f, 0.5f);
}

// ---------------------------------------------------------------------------
// Kernel 2 (R9): MLP restructure. R8 showed both pipes idle at unchanged
// duration -> request-latency-bound (~4 in-flight lines/wave, Little's law
// matches 1.9 TB/s). This version: 2 pixels/thread (independent chains) and
// the first TWO survivors of each pixel selected branchlessly, with ALL
// scattered gathers (2px x 2surv x {fn,bary,dists} = 12 loads) issued in ONE
// window before any dependent compute. Missing survivors use the dup address
// (L1 hit) with zero weight. Rare tail loop handles >=3 survivors
// (P(wave) ~ 0.35%). Selection via unrolled cndmask chains: static register
// indexing only.
// ---------------------------------------------------------------------------
__global__ __launch_bounds__(256) void normal_shader_q14_mlp(
    const int*   __restrict__ p2f,    // (N,H,W,K)
    const float* __restrict__ bary,   // (N,H,W,K,3)
    const float* __restrict__ zbuf,   // (N,H,W,K)
    const float* __restrict__ dists,  // (N,H,W,K)
    const uint4* __restrict__ fn,     // (F) packed face normals
    float*       __restrict__ out)    // (N,H,W,3)
{
    const int t = blockIdx.x * blockDim.x + threadIdx.x;
    if (t >= NPIX2) return;
    const int p0 = t;
    const int p1 = t + NPIX2;

    // ---- streams for BOTH pixels: 8 coalesced vector loads in flight ----
    const int4*   pfA = reinterpret_cast<const int4*>(p2f + (size_t)p0 * KF);
    const int4*   pfB = reinterpret_cast<const int4*>(p2f + (size_t)p1 * KF);
    const float4* zA  = reinterpret_cast<const float4*>(zbuf + (size_t)p0 * KF);
    const float4* zB  = reinterpret_cast<const float4*>(zbuf + (size_t)p1 * KF);
    int4   fa0 = pfA[0], fb0 = pfA[1];
    int4   fa1 = pfB[0], fb1 = pfB[1];
    float4 za0 = zA[0],  zb0 = zA[1];
    float4 za1 = zB[0],  zb1 = zB[1];

    int f0[KF] = {fa0.x, fa0.y, fa0.z, fa0.w, fb0.x, fb0.y, fb0.z, fb0.w};
    int f1[KF] = {fa1.x, fa1.y, fa1.z, fa1.w, fb1.x, fb1.y, fb1.z, fb1.w};
    float zv0[KF] = {za0.x, za0.y, za0.z, za0.w, zb0.x, zb0.y, zb0.z, zb0.w};
    float zv1[KF] = {za1.x, za1.y, za1.z, za1.w, zb1.x, zb1.y, zb1.z, zb1.w};

    // ---- z_inv + max + survivor mask, both pixels ----
    float zinv0[KF], zinv1[KF];
    float zmax0 = EPSV, zmax1 = EPSV;
#pragma unroll
    for (int k = 0; k < KF; ++k) {
        const float zi0 = (f0[k] >= 0) ? (ZFAR - zv0[k]) * (1.0f / (ZFAR - ZNEAR)) : 0.0f;
        const float zi1 = (f1[k] >= 0) ? (ZFAR - zv1[k]) * (1.0f / (ZFAR - ZNEAR)) : 0.0f;
        zinv0[k] = zi0; zinv1[k] = zi1;
        zmax0 = fmaxf(zmax0, zi0);
        zmax1 = fmaxf(zmax1, zi1);
    }
    const float zcut0 = zmax0 - ZWIN;
    const float zcut1 = zmax1 - ZWIN;
    unsigned rem0 = 0u, rem1 = 0u;
#pragma unroll
    for (int k = 0; k < KF; ++k) {
        if (f0[k] >= 0 && zinv0[k] > zcut0) rem0 |= (1u << k);
        if (f1[k] >= 0 && zinv1[k] > zcut1) rem1 |= (1u << k);
    }

    // ---- branchless selection of survivors #1 and #2 for both pixels ----
    int k00 = 0, g00 = 0; float z00 = 0.0f;
#pragma unroll
    for (int k = KF - 1; k >= 0; --k)
        if (rem0 & (1u << k)) { k00 = k; g00 = f0[k]; z00 = zinv0[k]; }
    const float v00 = (rem0 != 0u) ? 1.0f : 0.0f;
    const unsigned r10 = rem0 & (rem0 - 1u);      // rem0==0 -> 0

    int k01 = k00, g01 = g00; float z01 = z00;
#pragma unroll
    for (int k = KF - 1; k >= 0; --k)
        if (r10 & (1u << k)) { k01 = k; g01 = f0[k]; z01 = zinv0[k]; }
    const float v01 = (r10 != 0u) ? 1.0f : 0.0f;
    unsigned r20 = r10 ? (r10 & (r10 - 1u)) : 0u;

    int k10 = 0, g10 = 0; float z10 = 0.0f;
#pragma unroll
    for (int k = KF - 1; k >= 0; --k)
        if (rem1 & (1u << k)) { k10 = k; g10 = f1[k]; z10 = zinv1[k]; }
    const float v10 = (rem1 != 0u) ? 1.0f : 0.0f;
    const unsigned r11 = rem1 & (rem1 - 1u);

    int k11 = k10, g11 = g10; float z11 = z10;
#pragma unroll
    for (int k = KF - 1; k >= 0; --k)
        if (r11 & (1u << k)) { k11 = k; g11 = f1[k]; z11 = zinv1[k]; }
    const float v11 = (r11 != 0u) ? 1.0f : 0.0f;
    unsigned r21 = r11 ? (r11 & (r11 - 1u)) : 0u;

    // ---- issue ALL scattered gathers in one window (12 loads) ----
    const size_t s00 = (size_t)p0 * KF + (size_t)k00;
    const size_t s01 = (size_t)p0 * KF + (size_t)k01;
    const size_t s10 = (size_t)p1 * KF + (size_t)k10;
    const size_t s11 = (size_t)p1 * KF + (size_t)k11;

    const uint4 q00 = fn[g00];
    const uint4 q01 = fn[g01];
    const uint4 q10 = fn[g10];
    const uint4 q11 = fn[g11];

    const float b000 = bary[s00 * 3 + 0], b001 = bary[s00 * 3 + 1], b002 = bary[s00 * 3 + 2];
    const float b010 = bary[s01 * 3 + 0], b011 = bary[s01 * 3 + 1], b012 = bary[s01 * 3 + 2];
    const float b100 = bary[s10 * 3 + 0], b101 = bary[s10 * 3 + 1], b102 = bary[s10 * 3 + 2];
    const float b110 = bary[s11 * 3 + 0], b111 = bary[s11 * 3 + 1], b112 = bary[s11 * 3 + 2];

    const float d00 = dists[s00];
    const float d01 = dists[s01];
    const float d10 = dists[s10];
    const float d11 = dists[s11];

    // ---- compute phase ----
    float ax0 = 0.0f, ay0 = 0.0f, az0 = 0.0f, wt0 = 0.0f;
    float ax1 = 0.0f, ay1 = 0.0f, az1 = 0.0f, wt1 = 0.0f;
    acc_one(q00, b000, b001, b002, d00, z00, zmax0, v00, ax0, ay0, az0, wt0);
    acc_one(q01, b010, b011, b012, d01, z01, zmax0, v01, ax0, ay0, az0, wt0);
    acc_one(q10, b100, b101, b102, d10, z10, zmax1, v10, ax1, ay1, az1, wt1);
    acc_one(q11, b110, b111, b112, d11, z11, zmax1, v11, ax1, ay1, az1, wt1);

    // ---- rare tail: >=3 survivors (P(lane) ~ 5e-5) ----
    while (r20) {
        int ks = 0, gs = 0; float zs = 0.0f;
#pragma unroll
        for (int k = KF - 1; k >= 0; --k)
            if (r20 & (1u << k)) { ks = k; gs = f0[k]; zs = zinv0[k]; }
        r20 &= r20 - 1u;
        const size_t s = (size_t)p0 * KF + (size_t)ks;
        const uint4 q = fn[gs];
        acc_one(q, bary[s * 3 + 0], bary[s * 3 + 1], bary[s * 3 + 2],
                dists[s], zs, zmax0, 1.0f, ax0, ay0, az0, wt0);
    }
    while (r21) {
        int ks = 0, gs = 0; float zs = 0.0f;
#pragma unroll
        for (int k = KF - 1; k >= 0; --k)
            if (r21 & (1u << k)) { ks = k; gs = f1[k]; zs = zinv1[k]; }
        r21 &= r21 - 1u;
        const size_t s = (size_t)p1 * KF + (size_t)ks;
        const uint4 q = fn[gs];
        acc_one(q, bary[s * 3 + 0], bary[s * 3 + 1], bary[s * 3 + 2],
                dists[s], zs, zmax1, 1.0f, ax1, ay1, az1, wt1);
    }

    // ---- epilogue, both pixels ----
    finish_pixel(ax0, ay0, az0, wt0, zmax0, out + (size_t)p0 * 3);
    finish_pixel(ax1, ay1, az1, wt1, zmax1, out + (size_t)p1 * 3);
}

// ---------------------------------------------------------------------------
// Fallback (R1 kernel) in case d_ws is too small for the 3.2 MB table.
// ---------------------------------------------------------------------------
__global__ __launch_bounds__(256) void normal_shader_direct(
    const int*   __restrict__ p2f,
    const float* __restrict__ bary,
    const float* __restrict__ zbuf,
    const float* __restrict__ dists,
    const float* __restrict__ vnorm,
    const int*   __restrict__ faces,
    float*       __restrict__ out)
{
    const int p = blockIdx.x * blockDim.x + threadIdx.x;
    if (p >= NPIX) return;

    const int4* pf4 = reinterpret_cast<const int4*>(p2f + (size_t)p * KF);
    int4 fa = pf4[0], fb = pf4[1];
    int f[KF] = {fa.x, fa.y, fa.z, fa.w, fb.x, fb.y, fb.z, fb.w};

    const float4* z4 = reinterpret_cast<const float4*>(zbuf + (size_t)p * KF);
    float4 za = z4[0], zb = z4[1];
    float zv[KF] = {za.x, za.y, za.z, za.w, zb.x, zb.y, zb.z, zb.w};

    const float4* d4 = reinterpret_cast<const float4*>(dists + (size_t)p * KF);
    float4 da = d4[0], db = d4[1];
    float dv[KF] = {da.x, da.y, da.z, da.w, db.x, db.y, db.z, db.w};

    const float4* b4 = reinterpret_cast<const float4*>(bary + (size_t)p * KF * 3);
    float bc[KF * 3];
#pragma unroll
    for (int i = 0; i < 6; ++i) {
        float4 t = b4[i];
        bc[4 * i + 0] = t.x; bc[4 * i + 1] = t.y;
        bc[4 * i + 2] = t.z; bc[4 * i + 3] = t.w;
    }

    float zinv[KF], prob[KF];
    float zmax = EPSV;
#pragma unroll
    for (int k = 0; k < KF; ++k) {
        const bool m = f[k] >= 0;
        const float zi = m ? (ZFAR - zv[k]) * (1.0f / (ZFAR - ZNEAR)) : 0.0f;
        const float pr = m ? 1.0f / (1.0f + __expf(dv[k] * SIGMA_INV)) : 0.0f;
        zinv[k] = zi;
        prob[k] = pr;
        zmax = fmaxf(zmax, zi);
    }

    float accx = 0.0f, accy = 0.0f, accz = 0.0f, wtot = 0.0f;
#pragma unroll
    for (int k = 0; k < KF; ++k) {
        const int idx = f[k] < 0 ? 0 : f[k];
        const int i3 = idx * 3;
        const int v0 = faces[i3 + 0];
        const int v1 = faces[i3 + 1];
        const int v2 = faces[i3 + 2];
        const float b0 = bc[k * 3 + 0];
        const float b1 = bc[k * 3 + 1];
        const float b2 = bc[k * 3 + 2];
        const float* n0 = vnorm + (size_t)v0 * 3;
        const float* n1 = vnorm + (size_t)v1 * 3;
        const float* n2 = vnorm + (size_t)v2 * 3;
        const float nx = b0 * n0[0] + b1 * n1[0] + b2 * n2[0];
        const float ny = b0 * n0[1] + b1 * n1[1] + b2 * n2[1];
        const float nz = b0 * n0[2] + b1 * n1[2] + b2 * n2[2];
        const float wgt = prob[k] * __expf((zinv[k] - zmax) * GAMMA_INV);
        wtot += wgt;
        accx = fmaf(wgt, nx, accx);
        accy = fmaf(wgt, ny, accy);
        accz = fmaf(wgt, nz, accz);
    }

    const float delta = fmaxf(__expf((EPSV - zmax) * GAMMA_INV), EPSV);
    const float inv_denom = 1.0f / (wtot + delta);
    const float r = (accx + delta) * inv_denom;
    const float g = (accy + delta) * inv_denom;
    const float b = (accz + delta) * inv_denom;

    const float nrm = sqrtf(r * r + g * g + b * b);
    const float invn = 1.0f / fmaxf(nrm, 1e-12f);

    float* o = out + (size_t)p * 3;
    o[0] = fmaf(r * invn, 0.5f, 0.5f);
    o[1] = fmaf(g * invn, 0.5f, 0.5f);
    o[2] = fmaf(b * invn, 0.5f, 0.5f);
}

extern "C" void kernel_launch(void* const* d_in, const int* in_sizes, int n_in,
                              void* d_out, int out_size, void* d_ws, size_t ws_size,
                              hipStream_t stream) {
    const int*   p2f   = (const int*)d_in[0];
    const float* bary  = (const float*)d_in[1];
    const float* zbuf  = (const float*)d_in[2];
    const float* dists = (const float*)d_in[3];
    const float* vnorm = (const float*)d_in[4];
    const int*   faces = (const int*)d_in[5];
    float* out = (float*)d_out;

    const int threads = 256;
    const size_t fn_bytes = (size_t)NFACES * sizeof(uint4);  // 3.2 MB

    if (ws_size >= fn_bytes) {
        uint4* fn = (uint4*)d_ws;
        pack_face_normals14<<<(NFACES + threads - 1) / threads, threads, 0, stream>>>(
            faces, vnorm, fn, NFACES);
        normal_shader_q14_mlp<<<(NPIX2 + threads - 1) / threads, threads, 0, stream>>>(
            p2f, bary, zbuf, dists, fn, out);
    } else {
        normal_shader_direct<<<(NPIX + threads - 1) / threads, threads, 0, stream>>>(
            p2f, bary, zbuf, dists, vnorm, faces, out);
    }
}

// Round 4
// 232.243 us; speedup vs baseline: 1.0286x; 1.0286x over previous
//
#include <hip/hip_runtime.h>

#define SIGMA_INV 1.0e4f          // 1/SIGMA
#define GAMMA_INV 1.0e4f          // 1/GAMMA
#define ZNEAR 1.0f
#define ZFAR 100.0f
#define EPSV 1e-10f

constexpr int KF = 8;
constexpr int NPIX = 4 * 512 * 512;
constexpr int NFACES = 200000;
// Dropped-slot relative weight <= e^LOG_CUT; worst-case amplification
// (prob ratio ~150 x normalize ~32x) -> ~5e-4, under the 3.9e-3 baseline.
#define LOG_CUT (-16.0f)
#define ZWIN (16.0f / GAMMA_INV)

// Native vector types for inline-asm register tuples (HIP's int4/float4 are
// structs -> not valid asm "v" tuple operands; suspected cause of R10's
// build failure).
typedef int      i32x4 __attribute__((ext_vector_type(4)));
typedef float    f32x4 __attribute__((ext_vector_type(4)));
typedef unsigned u32x4 __attribute__((ext_vector_type(4)));

// ---------------------------------------------------------------------------
// Kernel 1: pack the 3 vertex normals of each face into ONE uint4 (16 B).
// 9 components x 14-bit fixed point. Table = 3.2 MB -> L2-resident.
// ---------------------------------------------------------------------------
__global__ __launch_bounds__(256) void pack_face_normals14(
    const int*   __restrict__ faces,   // (F,3)
    const float* __restrict__ vnorm,   // (V,3)
    uint4*       __restrict__ fn,      // (F) packed
    int F)
{
    const int f = blockIdx.x * blockDim.x + threadIdx.x;
    if (f >= F) return;
    const int v[3] = { faces[f * 3 + 0], faces[f * 3 + 1], faces[f * 3 + 2] };

    unsigned long long lo = 0ull, hi = 0ull;
    int i = 0;
#pragma unroll
    for (int t = 0; t < 3; ++t) {
#pragma unroll
        for (int c = 0; c < 3; ++c, ++i) {
            const float x = vnorm[(size_t)v[t] * 3 + c];
            const unsigned long long code = (unsigned long long)(unsigned)
                __float2int_rn(fminf(fmaxf(x, -1.0f), 1.0f) * 8191.5f + 8191.5f);
            const int bp = 14 * i;
            if (bp < 64) {
                lo |= code << bp;
                if (bp > 50) hi |= code >> (64 - bp);
            } else {
                hi |= code << (bp - 64);
            }
        }
    }
    uint4 q;
    q.x = (unsigned)(lo & 0xFFFFFFFFull);
    q.y = (unsigned)(lo >> 32);
    q.z = (unsigned)(hi & 0xFFFFFFFFull);
    q.w = (unsigned)(hi >> 32);
    fn[f] = q;
}

__device__ __forceinline__ float dec14(const unsigned* w, int i) {
    const int bp = 14 * i;
    const int j = bp >> 5;
    const int off = bp & 31;
    unsigned long long u = (unsigned long long)w[j];
    if (j < 3) u |= (unsigned long long)w[j + 1] << 32;
    const unsigned code = (unsigned)(u >> off) & 0x3FFFu;
    return fmaf((float)code, 2.0f / 16383.0f, -1.0f);
}

// ---------------------------------------------------------------------------
// Kernel 2 (R11 = R10 hardened): R8 structure + sc0 (L1-bypass,
// L2-allocating) on every load. Evidence: R7/R8/R9 (three structures) and
// hot-vs-cold L3 replays all pin at 80-85 us while HBM bytes vary 0..2.6
// TB/s -> not BW-bound, not latency-bound (R9's batched independent gathers
// didn't help). The invariant is distinct-L1-line count: ~4.8 line
// FILLS/pixel x ~4 cy fill-port occupancy ~ observed ~25 cy/px. None of
// this data has per-CU L1 reuse, so bypass L1 entirely. sc0 != nt: nt
// bypasses L2 too (R7: 2x slower); sc0 keeps L2 allocation. Loads sit in
// monolithic asm blocks ending in s_waitcnt vmcnt(0) with early-clobber
// outputs, so consumers cannot be hoisted above the wait (rule #18).
// ---------------------------------------------------------------------------
__global__ __launch_bounds__(256) void normal_shader_q14_sc0(
    const int*   __restrict__ p2f,    // (N,H,W,K)
    const float* __restrict__ bary,   // (N,H,W,K,3)
    const float* __restrict__ zbuf,   // (N,H,W,K)
    const float* __restrict__ dists,  // (N,H,W,K)
    const uint4* __restrict__ fn,     // (F) packed face normals
    float*       __restrict__ out)    // (N,H,W,3)
{
    const int p = blockIdx.x * blockDim.x + threadIdx.x;
    if (p >= NPIX) return;

    // ---- coalesced stream loads (p2f + zbuf), L1-bypassed, one window ----
    const int*   pfp = p2f + (size_t)p * KF;
    const float* zp  = zbuf + (size_t)p * KF;

    i32x4 fa, fb;
    f32x4 za, zb;
    asm volatile(
        "global_load_dwordx4 %0, %4, off sc0\n\t"
        "global_load_dwordx4 %1, %5, off sc0\n\t"
        "global_load_dwordx4 %2, %6, off sc0\n\t"
        "global_load_dwordx4 %3, %7, off sc0\n\t"
        "s_waitcnt vmcnt(0)"
        : "=&v"(fa), "=&v"(fb), "=&v"(za), "=&v"(zb)
        : "v"(pfp), "v"(pfp + 4), "v"(zp), "v"(zp + 4)
        : "memory");

    int f[KF] = {fa[0], fa[1], fa[2], fa[3], fb[0], fb[1], fb[2], fb[3]};
    float zv[KF] = {za[0], za[1], za[2], za[3], zb[0], zb[1], zb[2], zb[3]};

    // ---- pass 1: z_inv + running max (no transcendentals, no bary) ----
    float zinv[KF];
    float zmax = EPSV;
#pragma unroll
    for (int k = 0; k < KF; ++k) {
        const float zi = (f[k] >= 0) ? (ZFAR - zv[k]) * (1.0f / (ZFAR - ZNEAR))
                                     : 0.0f;
        zinv[k] = zi;
        zmax = fmaxf(zmax, zi);
    }

    // ---- survivor bitmask: valid slot within ZWIN of the max ----
    const float zcut = zmax - ZWIN;
    unsigned rem = 0u;
#pragma unroll
    for (int k = 0; k < KF; ++k)
        if (f[k] >= 0 && zinv[k] > zcut) rem |= (1u << k);

    // ---- survivor loop: ~1.05 full-wave iterations ----
    float accx = 0.0f, accy = 0.0f, accz = 0.0f, wtot = 0.0f;
    while (rem) {
        // select lowest surviving slot via unrolled cndmask chain
        int ksel = 0, fsel = 0;
        float zsel = 0.0f;
#pragma unroll
        for (int k = KF - 1; k >= 0; --k) {
            if (rem & (1u << k)) { ksel = k; fsel = f[k]; zsel = zinv[k]; }
        }
        rem &= rem - 1u;   // clear that (lowest) bit

        // scattered gathers, L1-bypassed, one window:
        // fn (16B) + bary (3x4B) + dists (4B)
        const size_t sidx = (size_t)p * KF + (size_t)ksel;
        const unsigned* qp = reinterpret_cast<const unsigned*>(fn + fsel);
        const float*    bp = bary + sidx * 3;
        const float*    dp = dists + sidx;

        u32x4 q;
        float b0, b1, b2, dvs;
        asm volatile(
            "global_load_dwordx4 %0, %5, off sc0\n\t"
            "global_load_dword %1, %6, off sc0\n\t"
            "global_load_dword %2, %7, off sc0\n\t"
            "global_load_dword %3, %8, off sc0\n\t"
            "global_load_dword %4, %9, off sc0\n\t"
            "s_waitcnt vmcnt(0)"
            : "=&v"(q), "=&v"(b0), "=&v"(b1), "=&v"(b2), "=&v"(dvs)
            : "v"(qp), "v"(bp), "v"(bp + 1), "v"(bp + 2), "v"(dp)
            : "memory");

        unsigned w[4] = { q[0], q[1], q[2], q[3] };
        const float nx = b0 * dec14(w, 0) + b1 * dec14(w, 3) + b2 * dec14(w, 6);
        const float ny = b0 * dec14(w, 1) + b1 * dec14(w, 4) + b2 * dec14(w, 7);
        const float nz = b0 * dec14(w, 2) + b1 * dec14(w, 5) + b2 * dec14(w, 8);

        const float prob = 1.0f / (1.0f + __expf(dvs * SIGMA_INV));
        const float wgt  = prob * __expf((zsel - zmax) * GAMMA_INV);
        wtot += wgt;
        accx = fmaf(wgt, nx, accx);
        accy = fmaf(wgt, ny, accy);
        accz = fmaf(wgt, nz, accz);
    }

    const float delta = fmaxf(__expf((EPSV - zmax) * GAMMA_INV), EPSV);
    const float inv_denom = 1.0f / (wtot + delta);
    const float r = (accx + delta) * inv_denom;   // bg = (1,1,1)
    const float g = (accy + delta) * inv_denom;
    const float b = (accz + delta) * inv_denom;

    const float nrm = sqrtf(r * r + g * g + b * b);
    const float invn = 1.0f / fmaxf(nrm, 1e-12f);

    float* o = out + (size_t)p * 3;
    o[0] = fmaf(r * invn, 0.5f, 0.5f);
    o[1] = fmaf(g * invn, 0.5f, 0.5f);
    o[2] = fmaf(b * invn, 0.5f, 0.5f);
}

// ---------------------------------------------------------------------------
// Fallback (R1 kernel) in case d_ws is too small for the 3.2 MB table.
// ---------------------------------------------------------------------------
__global__ __launch_bounds__(256) void normal_shader_direct(
    const int*   __restrict__ p2f,
    const float* __restrict__ bary,
    const float* __restrict__ zbuf,
    const float* __restrict__ dists,
    const float* __restrict__ vnorm,
    const int*   __restrict__ faces,
    float*       __restrict__ out)
{
    const int p = blockIdx.x * blockDim.x + threadIdx.x;
    if (p >= NPIX) return;

    const int4* pf4 = reinterpret_cast<const int4*>(p2f + (size_t)p * KF);
    int4 fa = pf4[0], fb = pf4[1];
    int f[KF] = {fa.x, fa.y, fa.z, fa.w, fb.x, fb.y, fb.z, fb.w};

    const float4* z4 = reinterpret_cast<const float4*>(zbuf + (size_t)p * KF);
    float4 za = z4[0], zb = z4[1];
    float zv[KF] = {za.x, za.y, za.z, za.w, zb.x, zb.y, zb.z, zb.w};

    const float4* d4 = reinterpret_cast<const float4*>(dists + (size_t)p * KF);
    float4 da = d4[0], db = d4[1];
    float dv[KF] = {da.x, da.y, da.z, da.w, db.x, db.y, db.z, db.w};

    const float4* b4 = reinterpret_cast<const float4*>(bary + (size_t)p * KF * 3);
    float bc[KF * 3];
#pragma unroll
    for (int i = 0; i < 6; ++i) {
        float4 t = b4[i];
        bc[4 * i + 0] = t.x; bc[4 * i + 1] = t.y;
        bc[4 * i + 2] = t.z; bc[4 * i + 3] = t.w;
    }

    float zinv[KF], prob[KF];
    float zmax = EPSV;
#pragma unroll
    for (int k = 0; k < KF; ++k) {
        const bool m = f[k] >= 0;
        const float zi = m ? (ZFAR - zv[k]) * (1.0f / (ZFAR - ZNEAR)) : 0.0f;
        const float pr = m ? 1.0f / (1.0f + __expf(dv[k] * SIGMA_INV)) : 0.0f;
        zinv[k] = zi;
        prob[k] = pr;
        zmax = fmaxf(zmax, zi);
    }

    float accx = 0.0f, accy = 0.0f, accz = 0.0f, wtot = 0.0f;
#pragma unroll
    for (int k = 0; k < KF; ++k) {
        const int idx = f[k] < 0 ? 0 : f[k];
        const int i3 = idx * 3;
        const int v0 = faces[i3 + 0];
        const int v1 = faces[i3 + 1];
        const int v2 = faces[i3 + 2];
        const float b0 = bc[k * 3 + 0];
        const float b1 = bc[k * 3 + 1];
        const float b2 = bc[k * 3 + 2];
        const float* n0 = vnorm + (size_t)v0 * 3;
        const float* n1 = vnorm + (size_t)v1 * 3;
        const float* n2 = vnorm + (size_t)v2 * 3;
        const float nx = b0 * n0[0] + b1 * n1[0] + b2 * n2[0];
        const float ny = b0 * n0[1] + b1 * n1[1] + b2 * n2[1];
        const float nz = b0 * n0[2] + b1 * n1[2] + b2 * n2[2];
        const float wgt = prob[k] * __expf((zinv[k] - zmax) * GAMMA_INV);
        wtot += wgt;
        accx = fmaf(wgt, nx, accx);
        accy = fmaf(wgt, ny, accy);
        accz = fmaf(wgt, nz, accz);
    }

    const float delta = fmaxf(__expf((EPSV - zmax) * GAMMA_INV), EPSV);
    const float inv_denom = 1.0f / (wtot + delta);
    const float r = (accx + delta) * inv_denom;
    const float g = (accy + delta) * inv_denom;
    const float b = (accz + delta) * inv_denom;

    const float nrm = sqrtf(r * r + g * g + b * b);
    const float invn = 1.0f / fmaxf(nrm, 1e-12f);

    float* o = out + (size_t)p * 3;
    o[0] = fmaf(r * invn, 0.5f, 0.5f);
    o[1] = fmaf(g * invn, 0.5f, 0.5f);
    o[2] = fmaf(b * invn, 0.5f, 0.5f);
}

extern "C" void kernel_launch(void* const* d_in, const int* in_sizes, int n_in,
                              void* d_out, int out_size, void* d_ws, size_t ws_size,
                              hipStream_t stream) {
    const int*   p2f   = (const int*)d_in[0];
    const float* bary  = (const float*)d_in[1];
    const float* zbuf  = (const float*)d_in[2];
    const float* dists = (const float*)d_in[3];
    const float* vnorm = (const float*)d_in[4];
    const int*   faces = (const int*)d_in[5];
    float* out = (float*)d_out;

    const int threads = 256;
    const size_t fn_bytes = (size_t)NFACES * sizeof(uint4);  // 3.2 MB

    if (ws_size >= fn_bytes) {
        uint4* fn = (uint4*)d_ws;
        pack_face_normals14<<<(NFACES + threads - 1) / threads, threads, 0, stream>>>(
            faces, vnorm, fn, NFACES);
        normal_shader_q14_sc0<<<(NPIX + threads - 1) / threads, threads, 0, stream>>>(
            p2f, bary, zbuf, dists, fn, out);
    } else {
        normal_shader_direct<<<(NPIX + threads - 1) / threads, threads, 0, stream>>>(
            p2f, bary, zbuf, dists, vnorm, faces, out);
    }
}

// Round 5
// 223.764 us; speedup vs baseline: 1.0676x; 1.0379x over previous
//
#include <hip/hip_runtime.h>

#define SIGMA_INV 1.0e4f          // 1/SIGMA
#define GAMMA_INV 1.0e4f          // 1/GAMMA
#define ZNEAR 1.0f
#define ZFAR 100.0f
#define EPSV 1e-10f

constexpr int KF = 8;
constexpr int NPIX = 4 * 512 * 512;
constexpr int NFACES = 200000;
// Dropped-slot relative weight <= e^LOG_CUT; worst-case amplification
// (prob ratio ~150 x normalize ~32x) -> ~5e-4, under the 3.9e-3 baseline.
#define LOG_CUT (-16.0f)
#define ZWIN (16.0f / GAMMA_INV)
// delta = exp(-zmax*1e4) < e^-100 ~ 0 when zmax > 0.01: single-survivor
// pixels then have rgb == n exactly (prob cancels) -> skip dists + exps.
#define ZMAX_SAFE 0.01f

// Native vector types for inline-asm register tuples (HIP's int4/float4 are
// structs -> not valid asm "v" tuple operands).
typedef int      i32x4 __attribute__((ext_vector_type(4)));
typedef float    f32x4 __attribute__((ext_vector_type(4)));
typedef unsigned u32x4 __attribute__((ext_vector_type(4)));
typedef float    f32x2 __attribute__((ext_vector_type(2), aligned(4)));

// ---------------------------------------------------------------------------
// Kernel 1: pack the 3 vertex normals of each face into ONE uint4 (16 B).
// 9 components x 14-bit fixed point. Table = 3.2 MB -> L2-resident.
// ---------------------------------------------------------------------------
__global__ __launch_bounds__(256) void pack_face_normals14(
    const int*   __restrict__ faces,   // (F,3)
    const float* __restrict__ vnorm,   // (V,3)
    uint4*       __restrict__ fn,      // (F) packed
    int F)
{
    const int f = blockIdx.x * blockDim.x + threadIdx.x;
    if (f >= F) return;
    const int v[3] = { faces[f * 3 + 0], faces[f * 3 + 1], faces[f * 3 + 2] };

    unsigned long long lo = 0ull, hi = 0ull;
    int i = 0;
#pragma unroll
    for (int t = 0; t < 3; ++t) {
#pragma unroll
        for (int c = 0; c < 3; ++c, ++i) {
            const float x = vnorm[(size_t)v[t] * 3 + c];
            const unsigned long long code = (unsigned long long)(unsigned)
                __float2int_rn(fminf(fmaxf(x, -1.0f), 1.0f) * 8191.5f + 8191.5f);
            const int bp = 14 * i;
            if (bp < 64) {
                lo |= code << bp;
                if (bp > 50) hi |= code >> (64 - bp);
            } else {
                hi |= code << (bp - 64);
            }
        }
    }
    uint4 q;
    q.x = (unsigned)(lo & 0xFFFFFFFFull);
    q.y = (unsigned)(lo >> 32);
    q.z = (unsigned)(hi & 0xFFFFFFFFull);
    q.w = (unsigned)(hi >> 32);
    fn[f] = q;
}

__device__ __forceinline__ float dec14(const unsigned* w, int i) {
    const int bp = 14 * i;
    const int j = bp >> 5;
    const int off = bp & 31;
    unsigned long long u = (unsigned long long)w[j];
    if (j < 3) u |= (unsigned long long)w[j + 1] << 32;
    const unsigned code = (unsigned)(u >> off) & 0x3FFFu;
    return fmaf((float)code, 2.0f / 16383.0f, -1.0f);
}

// ---------------------------------------------------------------------------
// Kernel 2 (R12): request-count reduction. Model from R0/R9/R11: duration
// ~ total TCP line-requests at ~5-6 cy each per CU (~45 cy/px), insensitive
// to bytes (R9: +50% bytes, equal time) and to data source (L3-hot replays
// identical). So cut requests:
//  (a) bary 3x dword -> 1x dwordx2; b2 = 1-b0-b1 (reference normalizes
//      barycentrics to sum=1; error ~1e-7).
//  (b) single-survivor pixels (~94%) with zmax > 0.01: delta < e^-100 -> 0,
//      so rgb == n (prob cancels) -> NO dists gather, NO sigmoid/exp.
// Requests/wave ~600 -> ~300. Streams + universal first gather keep R11's
// sc0 monolithic-asm form (loads + s_waitcnt vmcnt(0), early-clobber outs,
// rule #18 safe); rare heavy path (~6% lanes) is plain HIP.
// ---------------------------------------------------------------------------
__global__ __launch_bounds__(256) void normal_shader_q14_split(
    const int*   __restrict__ p2f,    // (N,H,W,K)
    const float* __restrict__ bary,   // (N,H,W,K,3)
    const float* __restrict__ zbuf,   // (N,H,W,K)
    const float* __restrict__ dists,  // (N,H,W,K)
    const uint4* __restrict__ fn,     // (F) packed face normals
    float*       __restrict__ out)    // (N,H,W,3)
{
    const int p = blockIdx.x * blockDim.x + threadIdx.x;
    if (p >= NPIX) return;

    // ---- coalesced stream loads (p2f + zbuf), one window, sc0 ----
    const int*   pfp = p2f + (size_t)p * KF;
    const float* zp  = zbuf + (size_t)p * KF;

    i32x4 fa, fb;
    f32x4 za, zb;
    asm volatile(
        "global_load_dwordx4 %0, %4, off sc0\n\t"
        "global_load_dwordx4 %1, %5, off sc0\n\t"
        "global_load_dwordx4 %2, %6, off sc0\n\t"
        "global_load_dwordx4 %3, %7, off sc0\n\t"
        "s_waitcnt vmcnt(0)"
        : "=&v"(fa), "=&v"(fb), "=&v"(za), "=&v"(zb)
        : "v"(pfp), "v"(pfp + 4), "v"(zp), "v"(zp + 4)
        : "memory");

    int f[KF] = {fa[0], fa[1], fa[2], fa[3], fb[0], fb[1], fb[2], fb[3]};
    float zv[KF] = {za[0], za[1], za[2], za[3], zb[0], zb[1], zb[2], zb[3]};

    // ---- pass 1: z_inv + running max ----
    float zinv[KF];
    float zmax = EPSV;
#pragma unroll
    for (int k = 0; k < KF; ++k) {
        const float zi = (f[k] >= 0) ? (ZFAR - zv[k]) * (1.0f / (ZFAR - ZNEAR))
                                     : 0.0f;
        zinv[k] = zi;
        zmax = fmaxf(zmax, zi);
    }

    // ---- survivor bitmask: valid slot within ZWIN of the max ----
    const float zcut = zmax - ZWIN;
    unsigned rem = 0u;
#pragma unroll
    for (int k = 0; k < KF; ++k)
        if (f[k] >= 0 && zinv[k] > zcut) rem |= (1u << k);

    // ---- first survivor (lowest bit) via unrolled cndmask chain ----
    int ksel = 0, fsel = 0;
    float zsel = 0.0f;
#pragma unroll
    for (int k = KF - 1; k >= 0; --k) {
        if (rem & (1u << k)) { ksel = k; fsel = f[k]; zsel = zinv[k]; }
    }
    const bool has = (rem != 0u);
    unsigned rem2 = rem & (rem - 1u);
    const bool heavy = (rem2 != 0u) || (zmax <= ZMAX_SAFE);

    // ---- universal gather: fn (x4) + bary (x2), sc0, one window ----
    // (fsel defaults to 0 for the ~0-probability rem==0 lanes: valid addr.)
    const size_t sidx = (size_t)p * KF + (size_t)ksel;
    const unsigned* qp = reinterpret_cast<const unsigned*>(fn + fsel);
    const float*    bp = bary + sidx * 3;

    u32x4 q;
    f32x2 b01;
    asm volatile(
        "global_load_dwordx4 %0, %2, off sc0\n\t"
        "global_load_dwordx2 %1, %3, off sc0\n\t"
        "s_waitcnt vmcnt(0)"
        : "=&v"(q), "=&v"(b01)
        : "v"(qp), "v"(bp)
        : "memory");

    unsigned w[4] = { q[0], q[1], q[2], q[3] };
    const float b0 = b01[0];
    const float b1 = b01[1];
    const float b2 = 1.0f - b0 - b1;   // reference normalizes bary to sum=1
    const float nx = b0 * dec14(w, 0) + b1 * dec14(w, 3) + b2 * dec14(w, 6);
    const float ny = b0 * dec14(w, 1) + b1 * dec14(w, 4) + b2 * dec14(w, 7);
    const float nz = b0 * dec14(w, 2) + b1 * dec14(w, 5) + b2 * dec14(w, 8);

    float accx = 0.0f, accy = 0.0f, accz = 0.0f, wtot = 0.0f;
    if (has) {
        if (!heavy) {
            // single survivor, delta ~ 0: rgb == n (prob cancels).
            accx = nx; accy = ny; accz = nz; wtot = 1.0f;
        } else {
            // exact path (~6% of lanes): needs prob + exp weights.
            const float dv0 = dists[sidx];
            const float pr0 = 1.0f / (1.0f + __expf(dv0 * SIGMA_INV));
            const float wg0 = pr0 * __expf((zsel - zmax) * GAMMA_INV);
            wtot = wg0;
            accx = wg0 * nx; accy = wg0 * ny; accz = wg0 * nz;

            while (rem2) {
                int ks = 0, gs = 0;
                float zs = 0.0f;
#pragma unroll
                for (int k = KF - 1; k >= 0; --k) {
                    if (rem2 & (1u << k)) { ks = k; gs = f[k]; zs = zinv[k]; }
                }
                rem2 &= rem2 - 1u;

                const size_t s2 = (size_t)p * KF + (size_t)ks;
                const uint4 q2 = fn[gs];
                const f32x2 bb =
                    *reinterpret_cast<const f32x2*>(bary + s2 * 3);
                const float dvs = dists[s2];

                unsigned w2[4] = { q2.x, q2.y, q2.z, q2.w };
                const float c0 = bb[0];
                const float c1 = bb[1];
                const float c2 = 1.0f - c0 - c1;
                const float mx = c0 * dec14(w2, 0) + c1 * dec14(w2, 3) + c2 * dec14(w2, 6);
                const float my = c0 * dec14(w2, 1) + c1 * dec14(w2, 4) + c2 * dec14(w2, 7);
                const float mz = c0 * dec14(w2, 2) + c1 * dec14(w2, 5) + c2 * dec14(w2, 8);

                const float prob = 1.0f / (1.0f + __expf(dvs * SIGMA_INV));
                const float wgt  = prob * __expf((zs - zmax) * GAMMA_INV);
                wtot += wgt;
                accx = fmaf(wgt, mx, accx);
                accy = fmaf(wgt, my, accy);
                accz = fmaf(wgt, mz, accz);
            }
        }
    }

    const float delta = fmaxf(__expf((EPSV - zmax) * GAMMA_INV), EPSV);
    const float inv_denom = 1.0f / (wtot + delta);
    const float r = (accx + delta) * inv_denom;   // bg = (1,1,1)
    const float g = (accy + delta) * inv_denom;
    const float b = (accz + delta) * inv_denom;

    const float nrm = sqrtf(r * r + g * g + b * b);
    const float invn = 1.0f / fmaxf(nrm, 1e-12f);

    float* o = out + (size_t)p * 3;
    o[0] = fmaf(r * invn, 0.5f, 0.5f);
    o[1] = fmaf(g * invn, 0.5f, 0.5f);
    o[2] = fmaf(b * invn, 0.5f, 0.5f);
}

// ---------------------------------------------------------------------------
// Fallback (R1 kernel) in case d_ws is too small for the 3.2 MB table.
// ---------------------------------------------------------------------------
__global__ __launch_bounds__(256) void normal_shader_direct(
    const int*   __restrict__ p2f,
    const float* __restrict__ bary,
    const float* __restrict__ zbuf,
    const float* __restrict__ dists,
    const float* __restrict__ vnorm,
    const int*   __restrict__ faces,
    float*       __restrict__ out)
{
    const int p = blockIdx.x * blockDim.x + threadIdx.x;
    if (p >= NPIX) return;

    const int4* pf4 = reinterpret_cast<const int4*>(p2f + (size_t)p * KF);
    int4 fa = pf4[0], fb = pf4[1];
    int f[KF] = {fa.x, fa.y, fa.z, fa.w, fb.x, fb.y, fb.z, fb.w};

    const float4* z4 = reinterpret_cast<const float4*>(zbuf + (size_t)p * KF);
    float4 za = z4[0], zb = z4[1];
    float zv[KF] = {za.x, za.y, za.z, za.w, zb.x, zb.y, zb.z, zb.w};

    const float4* d4 = reinterpret_cast<const float4*>(dists + (size_t)p * KF);
    float4 da = d4[0], db = d4[1];
    float dv[KF] = {da.x, da.y, da.z, da.w, db.x, db.y, db.z, db.w};

    const float4* b4 = reinterpret_cast<const float4*>(bary + (size_t)p * KF * 3);
    float bc[KF * 3];
#pragma unroll
    for (int i = 0; i < 6; ++i) {
        float4 t = b4[i];
        bc[4 * i + 0] = t.x; bc[4 * i + 1] = t.y;
        bc[4 * i + 2] = t.z; bc[4 * i + 3] = t.w;
    }

    float zinv[KF], prob[KF];
    float zmax = EPSV;
#pragma unroll
    for (int k = 0; k < KF; ++k) {
        const bool m = f[k] >= 0;
        const float zi = m ? (ZFAR - zv[k]) * (1.0f / (ZFAR - ZNEAR)) : 0.0f;
        const float pr = m ? 1.0f / (1.0f + __expf(dv[k] * SIGMA_INV)) : 0.0f;
        zinv[k] = zi;
        prob[k] = pr;
        zmax = fmaxf(zmax, zi);
    }

    float accx = 0.0f, accy = 0.0f, accz = 0.0f, wtot = 0.0f;
#pragma unroll
    for (int k = 0; k < KF; ++k) {
        const int idx = f[k] < 0 ? 0 : f[k];
        const int i3 = idx * 3;
        const int v0 = faces[i3 + 0];
        const int v1 = faces[i3 + 1];
        const int v2 = faces[i3 + 2];
        const float b0 = bc[k * 3 + 0];
        const float b1 = bc[k * 3 + 1];
        const float b2 = bc[k * 3 + 2];
        const float* n0 = vnorm + (size_t)v0 * 3;
        const float* n1 = vnorm + (size_t)v1 * 3;
        const float* n2 = vnorm + (size_t)v2 * 3;
        const float nx = b0 * n0[0] + b1 * n1[0] + b2 * n2[0];
        const float ny = b0 * n0[1] + b1 * n1[1] + b2 * n2[1];
        const float nz = b0 * n0[2] + b1 * n1[2] + b2 * n2[2];
        const float wgt = prob[k] * __expf((zinv[k] - zmax) * GAMMA_INV);
        wtot += wgt;
        accx = fmaf(wgt, nx, accx);
        accy = fmaf(wgt, ny, accy);
        accz = fmaf(wgt, nz, accz);
    }

    const float delta = fmaxf(__expf((EPSV - zmax) * GAMMA_INV), EPSV);
    const float inv_denom = 1.0f / (wtot + delta);
    const float r = (accx + delta) * inv_denom;
    const float g = (accy + delta) * inv_denom;
    const float b = (accz + delta) * inv_denom;

    const float nrm = sqrtf(r * r + g * g + b * b);
    const float invn = 1.0f / fmaxf(nrm, 1e-12f);

    float* o = out + (size_t)p * 3;
    o[0] = fmaf(r * invn, 0.5f, 0.5f);
    o[1] = fmaf(g * invn, 0.5f, 0.5f);
    o[2] = fmaf(b * invn, 0.5f, 0.5f);
}

extern "C" void kernel_launch(void* const* d_in, const int* in_sizes, int n_in,
                              void* d_out, int out_size, void* d_ws, size_t ws_size,
                              hipStream_t stream) {
    const int*   p2f   = (const int*)d_in[0];
    const float* bary  = (const float*)d_in[1];
    const float* zbuf  = (const float*)d_in[2];
    const float* dists = (const float*)d_in[3];
    const float* vnorm = (const float*)d_in[4];
    const int*   faces = (const int*)d_in[5];
    float* out = (float*)d_out;

    const int threads = 256;
    const size_t fn_bytes = (size_t)NFACES * sizeof(uint4);  // 3.2 MB

    if (ws_size >= fn_bytes) {
        uint4* fn = (uint4*)d_ws;
        pack_face_normals14<<<(NFACES + threads - 1) / threads, threads, 0, stream>>>(
            faces, vnorm, fn, NFACES);
        normal_shader_q14_split<<<(NPIX + threads - 1) / threads, threads, 0, stream>>>(
            p2f, bary, zbuf, dists, fn, out);
    } else {
        normal_shader_direct<<<(NPIX + threads - 1) / threads, threads, 0, stream>>>(
            p2f, bary, zbuf, dists, vnorm, faces, out);
    }
}